// Round 1
// baseline (436.904 us; speedup 1.0000x reference)
//
#include <hip/hip_runtime.h>

#define BATCH  2
#define DM     96
#define DI     192
#define NSTATE 16
#define RRANK  6
#define KDIR   6
#define L      4096
#define ROWW   40   // padded x_dbl row: [0..5]=dts, [8..23]=B, [24..39]=C

// spatial index (d,h,w flattened) for direction k at sequence position l
__device__ __forceinline__ int map_s(int k, int l) {
  int lp = (k & 1) ? (L - 1 - l) : l;
  int kb = k >> 1;
  if (kb == 0) return lp;                       // [d][h][w]
  int a = lp >> 8, b = (lp >> 4) & 15, c = lp & 15;
  if (kb == 1) return (b << 8) | (a << 4) | c;  // seq [h][d][w] -> spatial
  return (b << 8) | (c << 4) | a;               // seq [w][d][h] -> spatial
}

// xz = x @ W_in^T ; first DI channels -> xe (channel-major for conv), rest -> z (pos-major)
__global__ void k_xz(const float* __restrict__ x, const float* __restrict__ W_in,
                     float* __restrict__ xe_c, float* __restrict__ z) {
  __shared__ float xt[16][97];
  int blk = blockIdx.x;
  int b = blk >> 8;               // L/16 = 256 tiles per batch
  int s0 = (blk & 255) << 4;
  for (int i = threadIdx.x; i < 16 * DM; i += 256) {
    int p = i / DM, c = i - p * DM;
    xt[p][c] = x[((size_t)(b * L + s0 + p)) * DM + c];
  }
  __syncthreads();
  for (int i = threadIdx.x; i < 384 * 16; i += 256) {
    int oc = i >> 4, p = i & 15;
    const float* wr = W_in + oc * DM;
    float acc = 0.f;
    #pragma unroll 8
    for (int c = 0; c < DM; ++c) acc = fmaf(xt[p][c], wr[c], acc);
    int s = s0 + p;
    if (oc < DI) xe_c[((size_t)(b * DI + oc)) * L + s] = acc;
    else         z[((size_t)(b * L + s)) * DI + (oc - DI)] = acc;
  }
}

// depthwise 3x3x3 conv, pad 1, + bias, SiLU -> xc_t[b][s][c]
__global__ void k_conv(const float* __restrict__ xe_c, const float* __restrict__ conv_w,
                       const float* __restrict__ conv_b, float* __restrict__ xc_t) {
  __shared__ float ch[L];
  int b = blockIdx.x / DI, c = blockIdx.x % DI;
  const float* src = xe_c + ((size_t)(b * DI + c)) * L;
  for (int i = threadIdx.x; i < L; i += 256) ch[i] = src[i];
  float w[27];
  #pragma unroll
  for (int j = 0; j < 27; ++j) w[j] = conv_w[c * 27 + j];
  float bias = conv_b[c];
  __syncthreads();
  for (int i = threadIdx.x; i < L; i += 256) {
    int d = i >> 8, h = (i >> 4) & 15, iw = i & 15;
    float acc = bias;
    #pragma unroll
    for (int kd = 0; kd < 3; ++kd) {
      int dd = d + kd - 1;
      #pragma unroll
      for (int kh = 0; kh < 3; ++kh) {
        int hh = h + kh - 1;
        #pragma unroll
        for (int kw = 0; kw < 3; ++kw) {
          int wwp = iw + kw - 1;
          if ((unsigned)dd < 16u && (unsigned)hh < 16u && (unsigned)wwp < 16u)
            acc = fmaf(ch[(dd << 8) | (hh << 4) | wwp], w[kd * 9 + kh * 3 + kw], acc);
        }
      }
    }
    float sv = acc / (1.f + __expf(-acc));
    xc_t[((size_t)(b * L + i)) * DI + c] = sv;
  }
}

// x_dbl[b][k][l][.] = x_proj_w[k] @ xs[b,k,:,l]  (xs read via map_s from xc_t)
__global__ void k_proj(const float* __restrict__ xc_t, const float* __restrict__ xpw,
                       float* __restrict__ xdbl) {
  __shared__ float wp[38][193];
  __shared__ float xr[32][193];
  int blk = blockIdx.x;
  int lt = blk & 127;             // L/32 = 128
  int bk = blk >> 7;
  int k = bk % KDIR, b = bk / KDIR;
  int l0 = lt << 5;
  const float* wsrc = xpw + (size_t)k * 38 * DI;
  for (int i = threadIdx.x; i < 38 * DI; i += 256) {
    int dd = i / DI, cc = i - dd * DI;
    wp[dd][cc] = wsrc[i];
  }
  for (int i = threadIdx.x; i < 32 * DI; i += 256) {
    int lr = i / DI, cc = i - lr * DI;
    int s = map_s(k, l0 + lr);
    xr[lr][cc] = xc_t[((size_t)(b * L + s)) * DI + cc];
  }
  __syncthreads();
  for (int i = threadIdx.x; i < 32 * 38; i += 256) {
    int lr = i / 38, dd = i - lr * 38;
    float acc = 0.f;
    #pragma unroll 8
    for (int cc = 0; cc < DI; ++cc) acc = fmaf(xr[lr][cc], wp[dd][cc], acc);
    int col = dd < 6 ? dd : dd + 2;
    xdbl[((size_t)((b * KDIR + k) * L + l0 + lr)) * ROWW + col] = acc;
  }
}

#define LC    64
#define NCHUNK (L / LC)
#define HALO  64

// chunked selective scan with halo warm-up; atomicAdd merge into y_sum[b][s][c]
__global__ void __launch_bounds__(DI) k_scan(const float* __restrict__ xc_t,
    const float* __restrict__ xdbl, const float* __restrict__ dtw,
    const float* __restrict__ dtb, const float* __restrict__ A_logs,
    const float* __restrict__ Ds, float* __restrict__ y_sum) {
  int blk = blockIdx.x;
  int chk = blk % NCHUNK;
  int bk  = blk / NCHUNK;
  int k = bk % KDIR, b = bk / KDIR;
  int c = threadIdx.x;
  float wdt[RRANK];
  #pragma unroll
  for (int r = 0; r < RRANK; ++r) wdt[r] = dtw[(k * DI + c) * RRANK + r];
  float bias = dtb[k * DI + c];
  float Dv = Ds[k * DI + c];
  const float* alog = A_logs + (size_t)(k * DI + c) * NSTATE;
  bool fast = true;
  #pragma unroll
  for (int n = 0; n < NSTATE; ++n)
    fast = fast && (fabsf(__expf(alog[n]) - (float)(n + 1)) < 1e-4f);
  float h[NSTATE];
  #pragma unroll
  for (int n = 0; n < NSTATE; ++n) h[n] = 0.f;
  int lo = chk * LC;
  int ls = lo - HALO; if (ls < 0) ls = 0;
  const float* rb = xdbl + (size_t)(b * KDIR + k) * L * ROWW;

  if (fast) {  // A[n] == -(n+1): dA[n] = exp(-dt)^(n+1), 1 exp instead of 16
    for (int l = ls; l < lo + LC; ++l) {
      const float* row = rb + (size_t)l * ROWW;
      float dtv = bias;
      #pragma unroll
      for (int r = 0; r < RRANK; ++r) dtv = fmaf(row[r], wdt[r], dtv);
      dtv = (dtv > 20.f) ? dtv : log1pf(__expf(dtv));
      int s = map_s(k, l);
      float u = xc_t[((size_t)(b * L + s)) * DI + c];
      float dtu = dtv * u;
      float e1 = __expf(-dtv);
      float dA = 1.f, y = 0.f;
      #pragma unroll
      for (int n = 0; n < NSTATE; ++n) {
        dA *= e1;
        h[n] = fmaf(dA, h[n], dtu * row[8 + n]);
        y = fmaf(h[n], row[24 + n], y);
      }
      if (l >= lo)
        atomicAdd(&y_sum[((size_t)(b * L + s)) * DI + c], fmaf(Dv, u, y));
    }
  } else {     // generic fallback (not expected to be taken)
    for (int l = ls; l < lo + LC; ++l) {
      const float* row = rb + (size_t)l * ROWW;
      float dtv = bias;
      #pragma unroll
      for (int r = 0; r < RRANK; ++r) dtv = fmaf(row[r], wdt[r], dtv);
      dtv = (dtv > 20.f) ? dtv : log1pf(__expf(dtv));
      int s = map_s(k, l);
      float u = xc_t[((size_t)(b * L + s)) * DI + c];
      float dtu = dtv * u;
      float y = 0.f;
      #pragma unroll
      for (int n = 0; n < NSTATE; ++n) {
        float dA = __expf(dtv * (-__expf(alog[n])));
        h[n] = fmaf(dA, h[n], dtu * row[8 + n]);
        y = fmaf(h[n], row[24 + n], y);
      }
      if (l >= lo)
        atomicAdd(&y_sum[((size_t)(b * L + s)) * DI + c], fmaf(Dv, u, y));
    }
  }
}

// LayerNorm(DI) -> *ln_w+ln_b -> *silu(z) -> @ W_out^T
__global__ void __launch_bounds__(DI) k_final(const float* __restrict__ y_sum,
    const float* __restrict__ zb, const float* __restrict__ lnw,
    const float* __restrict__ lnb, const float* __restrict__ W_out,
    float* __restrict__ out) {
  __shared__ float red[6];
  __shared__ float ys[DI];
  int p = blockIdx.x;
  int c = threadIdx.x;
  float v = y_sum[(size_t)p * DI + c];
  float s1 = v, s2 = v * v;
  #pragma unroll
  for (int m = 32; m >= 1; m >>= 1) {
    s1 += __shfl_xor(s1, m, 64);
    s2 += __shfl_xor(s2, m, 64);
  }
  if ((c & 63) == 0) { red[c >> 6] = s1; red[3 + (c >> 6)] = s2; }
  __syncthreads();
  float mu  = (red[0] + red[1] + red[2]) * (1.f / DI);
  float var = (red[3] + red[4] + red[5]) * (1.f / DI) - mu * mu;
  float yln = (v - mu) * rsqrtf(var + 1e-5f) * lnw[c] + lnb[c];
  float g = zb[(size_t)p * DI + c];
  ys[c] = yln * (g / (1.f + __expf(-g)));
  __syncthreads();
  if (c < DM) {
    const float* wr = W_out + c * DI;
    float acc = 0.f;
    #pragma unroll 8
    for (int j = 0; j < DI; ++j) acc = fmaf(ys[j], wr[j], acc);
    out[(size_t)p * DM + c] = acc;
  }
}

extern "C" void kernel_launch(void* const* d_in, const int* in_sizes, int n_in,
                              void* d_out, int out_size, void* d_ws, size_t ws_size,
                              hipStream_t stream) {
  const float* x        = (const float*)d_in[0];
  const float* W_in     = (const float*)d_in[1];
  const float* conv_w   = (const float*)d_in[2];
  const float* conv_b   = (const float*)d_in[3];
  const float* x_proj_w = (const float*)d_in[4];
  const float* dt_proj_w= (const float*)d_in[5];
  const float* dt_proj_b= (const float*)d_in[6];
  const float* A_logs   = (const float*)d_in[7];
  const float* Ds       = (const float*)d_in[8];
  const float* ln_w     = (const float*)d_in[9];
  const float* ln_b     = (const float*)d_in[10];
  const float* W_out    = (const float*)d_in[11];
  float* out = (float*)d_out;

  float* ws   = (float*)d_ws;
  float* xe_c = ws;                                    // B*DI*L
  float* zb   = xe_c + (size_t)BATCH * DI * L;         // B*L*DI
  float* xc_t = zb   + (size_t)BATCH * L * DI;         // B*L*DI
  float* xdbl = xc_t + (size_t)BATCH * L * DI;         // B*K*L*ROWW
  float* ysum = xdbl + (size_t)BATCH * KDIR * L * ROWW;// B*L*DI

  hipMemsetAsync(ysum, 0, (size_t)BATCH * L * DI * sizeof(float), stream);
  k_xz  <<<BATCH * (L / 16), 256, 0, stream>>>(x, W_in, xe_c, zb);
  k_conv<<<BATCH * DI,       256, 0, stream>>>(xe_c, conv_w, conv_b, xc_t);
  k_proj<<<BATCH * KDIR * (L / 32), 256, 0, stream>>>(xc_t, x_proj_w, xdbl);
  k_scan<<<BATCH * KDIR * NCHUNK, DI, 0, stream>>>(xc_t, xdbl, dt_proj_w, dt_proj_b,
                                                   A_logs, Ds, ysum);
  k_final<<<BATCH * L, DI, 0, stream>>>(ysum, zb, ln_w, ln_b, W_out, out);
}

// Round 2
// 265.654 us; speedup vs baseline: 1.6446x; 1.6446x over previous
//
#include <hip/hip_runtime.h>

#define BATCH  2
#define DM     96
#define DI     192
#define NSTATE 16
#define RRANK  6
#define KDIR   6
#define L      4096
#define ROWW   40   // padded x_dbl row: [0..5]=dts, [6..7]=0, [8..23]=B, [24..39]=C
#define LC     64
#define NCHUNK (L / LC)
#define HALO   64

// spatial index (d,h,w flattened) for direction k at sequence position l
__device__ __forceinline__ int map_s(int k, int l) {
  int lp = (k & 1) ? (L - 1 - l) : l;
  int kb = k >> 1;
  if (kb == 0) return lp;                       // [d][h][w]
  int a = lp >> 8, b = (lp >> 4) & 15, c = lp & 15;
  if (kb == 1) return (b << 8) | (a << 4) | c;  // seq [h][d][w] -> spatial
  return (b << 8) | (c << 4) | a;               // seq [w][d][h] -> spatial
}

// ---------------- xz = x @ W_in^T -------------------------------------------
// block: 64 positions x 96-oc slice. LDS f4 tiles, 96 FMA per 10 ds_read_b128.
#define XZ_SP 25
__global__ __launch_bounds__(256) void k_xz(const float* __restrict__ x,
    const float* __restrict__ W_in, float* __restrict__ xe_c, float* __restrict__ z) {
  __shared__ float4 xt[64 * XZ_SP];
  __shared__ float4 wt[96 * XZ_SP];
  int blk = blockIdx.x;
  int slice = blk & 3, tile = (blk >> 2) & 63, b = blk >> 8;
  int s0 = tile << 6, oc0 = slice * 96;
  const float4* xg = (const float4*)(x + ((size_t)(b * L + s0)) * DM);
  for (int i = threadIdx.x; i < 64 * 24; i += 256) {
    int p = i / 24, q = i - p * 24;
    xt[p * XZ_SP + q] = xg[i];
  }
  const float4* wg = (const float4*)(W_in + (size_t)oc0 * DM);
  for (int i = threadIdx.x; i < 96 * 24; i += 256) {
    int r = i / 24, q = i - r * 24;
    wt[r * XZ_SP + q] = wg[i];
  }
  __syncthreads();
  int og = threadIdx.x & 15, pg = threadIdx.x >> 4;
  float acc[4][6];
  #pragma unroll
  for (int j = 0; j < 4; ++j)
    #pragma unroll
    for (int m = 0; m < 6; ++m) acc[j][m] = 0.f;
  for (int q = 0; q < 24; ++q) {
    float4 xv[4], wv[6];
    #pragma unroll
    for (int j = 0; j < 4; ++j) xv[j] = xt[(pg * 4 + j) * XZ_SP + q];
    #pragma unroll
    for (int m = 0; m < 6; ++m) wv[m] = wt[(og * 6 + m) * XZ_SP + q];
    #pragma unroll
    for (int j = 0; j < 4; ++j)
      #pragma unroll
      for (int m = 0; m < 6; ++m) {
        acc[j][m] = fmaf(xv[j].x, wv[m].x, acc[j][m]);
        acc[j][m] = fmaf(xv[j].y, wv[m].y, acc[j][m]);
        acc[j][m] = fmaf(xv[j].z, wv[m].z, acc[j][m]);
        acc[j][m] = fmaf(xv[j].w, wv[m].w, acc[j][m]);
      }
  }
  if (slice < 2) {
    #pragma unroll
    for (int m = 0; m < 6; ++m) {
      int oc = oc0 + og * 6 + m;
      float4 v = make_float4(acc[0][m], acc[1][m], acc[2][m], acc[3][m]);
      *(float4*)(xe_c + ((size_t)(b * DI + oc)) * L + s0 + pg * 4) = v;
    }
  } else {
    #pragma unroll
    for (int j = 0; j < 4; ++j)
      #pragma unroll
      for (int m = 0; m < 6; ++m) {
        int zc = (oc0 - DI) + og * 6 + m;
        z[((size_t)(b * L + s0 + pg * 4 + j)) * DI + zc] = acc[j][m];
      }
  }
}

// ---------------- depthwise conv3d + SiLU, channel-major out ----------------
__global__ __launch_bounds__(256) void k_conv(const float* __restrict__ xe_c,
    const float* __restrict__ conv_w, const float* __restrict__ conv_b,
    float* __restrict__ xc_c) {
  __shared__ float ch[L];
  int b = blockIdx.x / DI, c = blockIdx.x % DI;
  const float4* src = (const float4*)(xe_c + ((size_t)(b * DI + c)) * L);
  for (int i = threadIdx.x; i < L / 4; i += 256) ((float4*)ch)[i] = src[i];
  float w[27];
  #pragma unroll
  for (int j = 0; j < 27; ++j) w[j] = conv_w[c * 27 + j];
  float bias = conv_b[c];
  __syncthreads();
  float* dst = xc_c + ((size_t)(b * DI + c)) * L;
  for (int i = threadIdx.x; i < L; i += 256) {
    int d = i >> 8, h = (i >> 4) & 15, iw = i & 15;
    float acc = bias;
    #pragma unroll
    for (int kd = 0; kd < 3; ++kd) {
      int dd = d + kd - 1;
      #pragma unroll
      for (int kh = 0; kh < 3; ++kh) {
        int hh = h + kh - 1;
        #pragma unroll
        for (int kw = 0; kw < 3; ++kw) {
          int wwp = iw + kw - 1;
          if ((unsigned)dd < 16u && (unsigned)hh < 16u && (unsigned)wwp < 16u)
            acc = fmaf(ch[(dd << 8) | (hh << 4) | wwp], w[kd * 9 + kh * 3 + kw], acc);
        }
      }
    }
    dst[i] = acc / (1.f + __expf(-acc));
  }
}

// ---------------- transpose [b][c][s] -> [b][s][c] --------------------------
__global__ __launch_bounds__(256) void k_tr(const float* __restrict__ src,
                                            float* __restrict__ dst) {
  __shared__ float t[32][33];
  int blk = blockIdx.x;
  int st = blk & 127, ct = (blk >> 7) % 6, b = blk / (128 * 6);
  int s0 = st << 5, c0 = ct << 5;
  int i = threadIdx.x >> 5, j = threadIdx.x & 31;
  #pragma unroll
  for (int k2 = 0; k2 < 4; ++k2)
    t[i + 8 * k2][j] = src[((size_t)(b * DI + c0 + i + 8 * k2)) * L + s0 + j];
  __syncthreads();
  #pragma unroll
  for (int k2 = 0; k2 < 4; ++k2)
    dst[((size_t)(b * L + s0 + i + 8 * k2)) * DI + c0 + j] = t[j][i + 8 * k2];
}

// ---------------- x_dbl = x_proj_w[k] @ xs rows -----------------------------
#define PJ_SP 49
__global__ __launch_bounds__(256) void k_proj(const float* __restrict__ xc_t,
    const float* __restrict__ xpw, float* __restrict__ xdbl) {
  __shared__ float4 wp[38 * PJ_SP];
  __shared__ float4 xr[32 * PJ_SP];
  __shared__ float  xd[32][ROWW];
  int blk = blockIdx.x;
  int lt = blk & 127, bk = blk >> 7;
  int k = bk % KDIR, b = bk / KDIR;
  int l0 = lt << 5;
  const float4* wsrc = (const float4*)(xpw + (size_t)k * 38 * DI);
  for (int i = threadIdx.x; i < 38 * 48; i += 256) {
    int r = i / 48, q = i - r * 48;
    wp[r * PJ_SP + q] = wsrc[i];
  }
  const float4* xsrc = (const float4*)xc_t;
  for (int i = threadIdx.x; i < 32 * 48; i += 256) {
    int lr = i / 48, q = i - lr * 48;
    int s = map_s(k, l0 + lr);
    xr[lr * PJ_SP + q] = xsrc[((size_t)(b * L + s)) * 48 + q];
  }
  if (threadIdx.x < 32) { xd[threadIdx.x][6] = 0.f; xd[threadIdx.x][7] = 0.f; }
  __syncthreads();
  int lr = threadIdx.x & 31, dg = threadIdx.x >> 5;
  float acc[5] = {0.f, 0.f, 0.f, 0.f, 0.f};
  for (int q = 0; q < 48; ++q) {
    float4 xv = xr[lr * PJ_SP + q];
    #pragma unroll
    for (int j = 0; j < 5; ++j) {
      int dd = dg * 5 + j;
      if (dd < 38) {
        float4 wv = wp[dd * PJ_SP + q];
        acc[j] = fmaf(xv.x, wv.x, acc[j]);
        acc[j] = fmaf(xv.y, wv.y, acc[j]);
        acc[j] = fmaf(xv.z, wv.z, acc[j]);
        acc[j] = fmaf(xv.w, wv.w, acc[j]);
      }
    }
  }
  #pragma unroll
  for (int j = 0; j < 5; ++j) {
    int dd = dg * 5 + j;
    if (dd < 38) xd[lr][dd < 6 ? dd : dd + 2] = acc[j];
  }
  __syncthreads();
  float4* xo = (float4*)(xdbl + (size_t)bk * L * ROWW + (size_t)l0 * ROWW);
  for (int i = threadIdx.x; i < 32 * 10; i += 256) {
    int lr2 = i / 10, q = i - lr2 * 10;
    xo[lr2 * 10 + q] = ((float4*)&xd[lr2][0])[q];
  }
}

// ---------------- chunked selective scan ------------------------------------
__global__ void __launch_bounds__(DI) k_scan(const float* __restrict__ xc_t,
    const float* __restrict__ xdbl, const float* __restrict__ dtw,
    const float* __restrict__ dtb, const float* __restrict__ A_logs,
    const float* __restrict__ Ds, float* __restrict__ y_sum) {
  __shared__ float4 rows[128 * 10];   // up to 128 rows x 40 floats
  int blk = blockIdx.x;
  int chk = blk & (NCHUNK - 1);
  int bk = blk >> 6;                  // NCHUNK == 64
  int k = bk % KDIR, b = bk / KDIR;
  int c = threadIdx.x;
  int lo = chk * LC;
  int ls = lo - HALO; if (ls < 0) ls = 0;
  int nr = lo + LC - ls;
  const float4* rsrc = (const float4*)(xdbl + (size_t)bk * L * ROWW) + (size_t)ls * 10;
  for (int i = c; i < nr * 10; i += DI) rows[i] = rsrc[i];
  float wdt[RRANK];
  #pragma unroll
  for (int r = 0; r < RRANK; ++r) wdt[r] = dtw[(k * DI + c) * RRANK + r];
  float bias = dtb[k * DI + c];
  float Dv = Ds[k * DI + c];
  const float* alog = A_logs + (size_t)(k * DI + c) * NSTATE;
  bool fast = true;
  #pragma unroll
  for (int n = 0; n < NSTATE; ++n)
    fast = fast && (fabsf(__expf(alog[n]) - (float)(n + 1)) < 1e-4f);
  float h[NSTATE];
  #pragma unroll
  for (int n = 0; n < NSTATE; ++n) h[n] = 0.f;
  const float* ub = xc_t + (size_t)b * L * DI + c;
  float* yb = y_sum + (size_t)b * L * DI + c;
  __syncthreads();

  int s_cur = map_s(k, ls);
  float u_cur = ub[(size_t)s_cur * DI];
  if (fast) {  // A[n] == -(n+1): dA[n] = e1^(n+1), log-depth powers
    for (int l = ls; l < lo + LC; ++l) {
      float u_nxt = u_cur; int s_nxt = s_cur;
      if (l + 1 < lo + LC) { s_nxt = map_s(k, l + 1); u_nxt = ub[(size_t)s_nxt * DI]; }
      const float4* rp = &rows[(l - ls) * 10];
      float4 r0 = rp[0], r1 = rp[1];
      float dtv = bias;
      dtv = fmaf(r0.x, wdt[0], dtv); dtv = fmaf(r0.y, wdt[1], dtv);
      dtv = fmaf(r0.z, wdt[2], dtv); dtv = fmaf(r0.w, wdt[3], dtv);
      dtv = fmaf(r1.x, wdt[4], dtv); dtv = fmaf(r1.y, wdt[5], dtv);
      float sp = fmaxf(dtv, 0.f) + __logf(1.f + __expf(-fabsf(dtv)));
      float e1 = __expf(-sp);
      float dtu = sp * u_cur;
      float p2 = e1 * e1, p4 = p2 * p2;
      float dA[NSTATE];
      dA[0] = e1; dA[1] = p2; dA[2] = p2 * e1; dA[3] = p4;
      #pragma unroll
      for (int n = 4; n < NSTATE; ++n) dA[n] = dA[n - 4] * p4;
      float4 B0 = rp[2], B1 = rp[3], B2 = rp[4], B3 = rp[5];
      float4 C0 = rp[6], C1 = rp[7], C2 = rp[8], C3 = rp[9];
      float y = 0.f;
      h[0]  = fmaf(dA[0],  h[0],  dtu * B0.x); y = fmaf(h[0],  C0.x, y);
      h[1]  = fmaf(dA[1],  h[1],  dtu * B0.y); y = fmaf(h[1],  C0.y, y);
      h[2]  = fmaf(dA[2],  h[2],  dtu * B0.z); y = fmaf(h[2],  C0.z, y);
      h[3]  = fmaf(dA[3],  h[3],  dtu * B0.w); y = fmaf(h[3],  C0.w, y);
      h[4]  = fmaf(dA[4],  h[4],  dtu * B1.x); y = fmaf(h[4],  C1.x, y);
      h[5]  = fmaf(dA[5],  h[5],  dtu * B1.y); y = fmaf(h[5],  C1.y, y);
      h[6]  = fmaf(dA[6],  h[6],  dtu * B1.z); y = fmaf(h[6],  C1.z, y);
      h[7]  = fmaf(dA[7],  h[7],  dtu * B1.w); y = fmaf(h[7],  C1.w, y);
      h[8]  = fmaf(dA[8],  h[8],  dtu * B2.x); y = fmaf(h[8],  C2.x, y);
      h[9]  = fmaf(dA[9],  h[9],  dtu * B2.y); y = fmaf(h[9],  C2.y, y);
      h[10] = fmaf(dA[10], h[10], dtu * B2.z); y = fmaf(h[10], C2.z, y);
      h[11] = fmaf(dA[11], h[11], dtu * B2.w); y = fmaf(h[11], C2.w, y);
      h[12] = fmaf(dA[12], h[12], dtu * B3.x); y = fmaf(h[12], C3.x, y);
      h[13] = fmaf(dA[13], h[13], dtu * B3.y); y = fmaf(h[13], C3.y, y);
      h[14] = fmaf(dA[14], h[14], dtu * B3.z); y = fmaf(h[14], C3.z, y);
      h[15] = fmaf(dA[15], h[15], dtu * B3.w); y = fmaf(h[15], C3.w, y);
      if (l >= lo) atomicAdd(yb + (size_t)s_cur * DI, fmaf(Dv, u_cur, y));
      u_cur = u_nxt; s_cur = s_nxt;
    }
  } else {     // generic fallback
    for (int l = ls; l < lo + LC; ++l) {
      const float4* rp = &rows[(l - ls) * 10];
      const float* rf = (const float*)rp;
      float dtv = bias;
      #pragma unroll
      for (int r = 0; r < RRANK; ++r) dtv = fmaf(rf[r], wdt[r], dtv);
      float sp = fmaxf(dtv, 0.f) + __logf(1.f + __expf(-fabsf(dtv)));
      int s = map_s(k, l);
      float u = ub[(size_t)s * DI];
      float dtu = sp * u;
      float y = 0.f;
      #pragma unroll
      for (int n = 0; n < NSTATE; ++n) {
        float dA = __expf(sp * (-__expf(alog[n])));
        h[n] = fmaf(dA, h[n], dtu * rf[8 + n]);
        y = fmaf(h[n], rf[24 + n], y);
      }
      if (l >= lo) atomicAdd(yb + (size_t)s * DI, fmaf(Dv, u, y));
    }
  }
}

// ---------------- LN -> gate -> W_out ---------------------------------------
#define FN_SP 49
__global__ __launch_bounds__(256) void k_final(const float* __restrict__ y_sum,
    const float* __restrict__ zb, const float* __restrict__ lnw,
    const float* __restrict__ lnb, const float* __restrict__ W_out,
    float* __restrict__ out) {
  __shared__ float4 ys4[16 * FN_SP];
  float* ys = (float*)ys4;
  int p0 = blockIdx.x << 4;
  int t = threadIdx.x;
  const float4* yg = (const float4*)(y_sum + (size_t)p0 * DI);
  for (int i = t; i < 16 * 48; i += 256) {
    int r = i / 48, q = i - r * 48;
    ys4[r * FN_SP + q] = yg[i];
  }
  __syncthreads();
  {
    int r = t >> 4, lg = t & 15;
    float v[12], s1 = 0.f, s2 = 0.f;
    #pragma unroll
    for (int j2 = 0; j2 < 12; ++j2) {
      float vv = ys[r * (FN_SP * 4) + lg + 16 * j2];
      v[j2] = vv; s1 += vv; s2 += vv * vv;
    }
    #pragma unroll
    for (int m = 1; m < 16; m <<= 1) {
      s1 += __shfl_xor(s1, m, 64);
      s2 += __shfl_xor(s2, m, 64);
    }
    float mu = s1 * (1.f / DI);
    float var = s2 * (1.f / DI) - mu * mu;
    float rs = rsqrtf(var + 1e-5f);
    #pragma unroll
    for (int j2 = 0; j2 < 12; ++j2) {
      int cc = lg + 16 * j2;
      float g = zb[(size_t)(p0 + r) * DI + cc];
      float yl = (v[j2] - mu) * rs * lnw[cc] + lnb[cc];
      ys[r * (FN_SP * 4) + cc] = yl * (g / (1.f + __expf(-g)));
    }
  }
  __syncthreads();
  int oc = t % 96, pg = t / 96;       // pg in {0,1,2}; pg==2 idle
  if (pg < 2) {
    const float4* wg4 = (const float4*)W_out;
    float acc[8];
    #pragma unroll
    for (int j = 0; j < 8; ++j) acc[j] = 0.f;
    for (int q = 0; q < 48; ++q) {
      float4 wv = wg4[oc * 48 + q];
      #pragma unroll
      for (int pp = 0; pp < 8; ++pp) {
        float4 yv = ys4[(pg * 8 + pp) * FN_SP + q];
        acc[pp] = fmaf(yv.x, wv.x, acc[pp]);
        acc[pp] = fmaf(yv.y, wv.y, acc[pp]);
        acc[pp] = fmaf(yv.z, wv.z, acc[pp]);
        acc[pp] = fmaf(yv.w, wv.w, acc[pp]);
      }
    }
    #pragma unroll
    for (int pp = 0; pp < 8; ++pp)
      out[(size_t)(p0 + pg * 8 + pp) * DM + oc] = acc[pp];
  }
}

extern "C" void kernel_launch(void* const* d_in, const int* in_sizes, int n_in,
                              void* d_out, int out_size, void* d_ws, size_t ws_size,
                              hipStream_t stream) {
  const float* x        = (const float*)d_in[0];
  const float* W_in     = (const float*)d_in[1];
  const float* conv_w   = (const float*)d_in[2];
  const float* conv_b   = (const float*)d_in[3];
  const float* x_proj_w = (const float*)d_in[4];
  const float* dt_proj_w= (const float*)d_in[5];
  const float* dt_proj_b= (const float*)d_in[6];
  const float* A_logs   = (const float*)d_in[7];
  const float* Ds       = (const float*)d_in[8];
  const float* ln_w     = (const float*)d_in[9];
  const float* ln_b     = (const float*)d_in[10];
  const float* W_out    = (const float*)d_in[11];
  float* out = (float*)d_out;

  float* ws   = (float*)d_ws;
  float* regA = ws;                                    // xe_c, later ysum (B*DI*L)
  float* zb   = regA + (size_t)BATCH * DI * L;
  float* xc_c = zb   + (size_t)BATCH * L * DI;
  float* xc_t = xc_c + (size_t)BATCH * L * DI;
  float* xdbl = xc_t + (size_t)BATCH * L * DI;         // B*K*L*ROWW

  k_xz  <<<BATCH * 64 * 4, 256, 0, stream>>>(x, W_in, regA, zb);
  k_conv<<<BATCH * DI,     256, 0, stream>>>(regA, conv_w, conv_b, xc_c);
  k_tr  <<<BATCH * 6 * 128, 256, 0, stream>>>(xc_c, xc_t);
  hipMemsetAsync(regA, 0, (size_t)BATCH * L * DI * sizeof(float), stream);  // ysum
  k_proj<<<BATCH * KDIR * 128, 256, 0, stream>>>(xc_t, x_proj_w, xdbl);
  k_scan<<<BATCH * KDIR * NCHUNK, DI, 0, stream>>>(xc_t, xdbl, dt_proj_w, dt_proj_b,
                                                   A_logs, Ds, regA);
  k_final<<<BATCH * L / 16, 256, 0, stream>>>(regA, zb, ln_w, ln_b, W_out, out);
}